// Round 12
// baseline (373.165 us; speedup 1.0000x reference)
//
#include <hip/hip_runtime.h>
#include <hip/hip_bf16.h>

typedef __attribute__((ext_vector_type(8))) short short8;   // 8 x bf16 bits = 4 VGPRs
typedef __attribute__((ext_vector_type(4))) float f32x4;

#define NW 8            // waves per block (512 threads)
#define BPW 8           // batches per wave (cols 8-15 of MFMA duplicate cols 0-7)
#define BPB (NW * BPW)  // 64 batches per block

static __device__ __forceinline__ unsigned pk_bf16(float a, float b) {
    unsigned d;
    asm("v_cvt_pk_bf16_f32 %0, %1, %2" : "=v"(d) : "v"(a), "v"(b));
    return d;
}

static __device__ __forceinline__ unsigned rne16(float x) {
    unsigned u = __float_as_uint(x);
    return (u + 0x7fffu + ((u >> 16) & 1u)) >> 16;
}
static __device__ __forceinline__ unsigned rne_bf16_pair(float x, float y) {
    return rne16(x) | (rne16(y) << 16);
}

static __device__ __forceinline__ short8 pack_frag(f32x4 a, f32x4 b) {
    union { unsigned u[4]; short8 s; } u;
    u.u[0] = pk_bf16(a.x, a.y);
    u.u[1] = pk_bf16(a.z, a.w);
    u.u[2] = pk_bf16(b.x, b.y);
    u.u[3] = pk_bf16(b.z, b.w);
    return u.s;
}

// Stage fragments of W (W[n][k]) into LDS. Entry idx = (kt*nct + ct)*64 + lane;
// lane holds 8 bf16 with k = kt*32 + (lane>>4)*8 + j, outer = ct*16 + (lane&15).
static __device__ __forceinline__ void stage_bfrags(const float* __restrict__ w,
                                                    int row_stride, int k_off, int nct,
                                                    short8* lds, int tid) {
    const int total = 4 * nct * 64;
    for (int idx = tid; idx < total; idx += NW * 64) {
        int lane = idx & 63;
        int ct = (idx >> 6) % nct;
        int kt = idx / (64 * nct);
        int n = ct * 16 + (lane & 15);
        int k = kt * 32 + (lane >> 4) * 8;
        const float* p = w + (size_t)n * row_stride + k_off + k;
        f32x4 a = *(const f32x4*)p;
        f32x4 b = *(const f32x4*)(p + 4);
        lds[idx] = pack_frag(a, b);
    }
}

// Split each element into bf16 hi + bf16 residual (hi -> lds_hi, lo -> lds_lo).
static __device__ __forceinline__ void stage_bfrags_split(const float* __restrict__ w,
                                                          int row_stride, int nct,
                                                          short8* lds_hi, short8* lds_lo,
                                                          int tid) {
    const int total = 4 * nct * 64;
    for (int idx = tid; idx < total; idx += NW * 64) {
        int lane = idx & 63;
        int ct = (idx >> 6) % nct;
        int kt = idx / (64 * nct);
        int n = ct * 16 + (lane & 15);
        int k = kt * 32 + (lane >> 4) * 8;
        const float* p = w + (size_t)n * row_stride + k;
        f32x4 a = *(const f32x4*)p;
        f32x4 b = *(const f32x4*)(p + 4);
        float xs[8] = {a.x, a.y, a.z, a.w, b.x, b.y, b.z, b.w};
        union { unsigned u[4]; short8 s; } uh, ul;
#pragma unroll
        for (int q = 0; q < 4; ++q) {
            float x = xs[2 * q], y = xs[2 * q + 1];
            unsigned hx = rne16(x), hy = rne16(y);
            uh.u[q] = hx | (hy << 16);
            ul.u[q] = rne_bf16_pair(x - __uint_as_float(hx << 16),
                                    y - __uint_as_float(hy << 16));
        }
        lds_hi[idx] = uh.s;
        lds_lo[idx] = ul.s;
    }
}

// Coalesced issue of value tile l: 4 instructions, each 64 lanes x 16B = two
// full contiguous 512B rows (8 fully-consumed 128B lines per instr).
static __device__ __forceinline__ void issue_tile(const float* __restrict__ vbase,
                                                  int l, int lrow, int lcol,
                                                  f32x4 (&xf)[4]) {
#pragma unroll
    for (int j = 0; j < 4; ++j)
        xf[j] = *(const f32x4*)(vbase + (size_t)(2 * j + lrow) * 1152 + l * 128 + lcol * 4);
}

// Convert to bf16 and commit into the wave-private vstage with XOR-chunk
// swizzle: 16B bf16 chunk c of row r stored at chunk c^(r&7). Writes: 2-way
// banks (free). Reads (b128): <=4-way.
static __device__ __forceinline__ void commit_tile(unsigned* vs, const f32x4 (&xf)[4],
                                                   int lrow, int lcol) {
    int cb = lcol >> 1, half = lcol & 1;
#pragma unroll
    for (int j = 0; j < 4; ++j) {
        int r = 2 * j + lrow;
        int dw = r * 64 + ((cb ^ (r & 7)) << 2) + half * 2;
        uint2 pkw;
        pkw.x = pk_bf16(xf[j].x, xf[j].y);
        pkw.y = pk_bf16(xf[j].z, xf[j].w);
        *(uint2*)&vs[dw] = pkw;
    }
}

// One fused l-step. Reads tile l from vstage, issues tile l+2 into xfI,
// computes swapped logit GEMM + flash softmax + half-o update, then commits
// tile l+1 (arrived during the chain) from xfC. Depth-2: tiles l+1 and l+2
// are both in flight across the compute chain.
static __device__ __forceinline__ void stepv(int l, unsigned* vs,
                                             const short8* __restrict__ wlds,
                                             const unsigned (&hkp)[8][2],
                                             const f32x4* w2lds4,
                                             const float* __restrict__ vbase,
                                             int lane, int g, int b, int lo,
                                             int lrow, int lcol, int sq,
                                             float& m, float& s, float (&o)[2][8],
                                             f32x4 (&xfI)[4], f32x4 (&xfC)[4]) {
    short8 af[4];
#pragma unroll
    for (int kt = 0; kt < 4; ++kt) {
        int dw = b * 64 + (((kt * 4 + g) ^ b) << 2);
        af[kt] = *reinterpret_cast<const short8*>(&vs[dw]);
    }
    if (l + 2 < 9) issue_tile(vbase, l + 2, lrow, lcol, xfI);

    // swapped logit GEMM: acc[h-tile][batch-col], weights A from LDS, value B regs
    float pA = 0.f, pB = 0.f;
#pragma unroll
    for (int ct = 0; ct < 8; ++ct) {
        f32x4 acc;
        acc.x = __uint_as_float(hkp[ct][0] << 16);
        acc.y = __uint_as_float(hkp[ct][0] & 0xffff0000u);
        acc.z = __uint_as_float(hkp[ct][1] << 16);
        acc.w = __uint_as_float(hkp[ct][1] & 0xffff0000u);
#pragma unroll
        for (int kt = 0; kt < 4; ++kt)
            acc = __builtin_amdgcn_mfma_f32_16x16x32_bf16(
                wlds[(kt * 8 + ct) * 64 + lane], af[kt], acc, 0, 0, 0);
        f32x4 wv = w2lds4[ct * 4 + g];
        if (ct & 1) {
            pB += fmaxf(acc.x, 0.f) * wv.x;
            pB += fmaxf(acc.y, 0.f) * wv.y;
            pB += fmaxf(acc.z, 0.f) * wv.z;
            pB += fmaxf(acc.w, 0.f) * wv.w;
        } else {
            pA += fmaxf(acc.x, 0.f) * wv.x;
            pA += fmaxf(acc.y, 0.f) * wv.y;
            pA += fmaxf(acc.z, 0.f) * wv.z;
            pA += fmaxf(acc.w, 0.f) * wv.w;
        }
    }
    float p = pA + pB;
    p += __shfl_xor(p, 16);
    p += __shfl_xor(p, 32);
    float w = p;  // logit of batch b, in every lane of the column

    bool valid = (l <= sq);
    float mn = valid ? fmaxf(m, w) : m;
    float c = __expf(m - mn);
    float e = valid ? __expf(w - mn) : 0.f;
    s = s * c + e;
    m = mn;

    // half-o update: lanes lo<8 own kt 0,1; lanes lo>=8 own kt 2,3 (static select)
    short8 afq0 = (lo < 8) ? af[0] : af[2];
    short8 afq1 = (lo < 8) ? af[1] : af[3];
#pragma unroll
    for (int q = 0; q < 2; ++q) {
        union { short8 v; unsigned u[4]; } uh;
        uh.v = q ? afq1 : afq0;
#pragma unroll
        for (int t = 0; t < 4; ++t) {
            float h0 = __uint_as_float(uh.u[t] << 16);
            float h1 = __uint_as_float(uh.u[t] & 0xffff0000u);
            o[q][2 * t]     = o[q][2 * t] * c + e * h0;
            o[q][2 * t + 1] = o[q][2 * t + 1] * c + e * h1;
        }
    }

    if (l + 1 < 9) commit_tile(vs, xfC, lrow, lcol);
}

// MEASURED launch-bounds rule on gfx950 hipcc: VGPR cap = 256/arg, independent
// of block size ((512,4)->64, (512,3)->84, (256,3)->84, (512,2)->128).
// R12: BPW=8 to make everything fit WELL below the 128 cap (~106 est):
// coalesced value loads (2 full rows / instr), depth-2 prefetch (8KB/wave in
// flight), LDS-transposed MFMA fragments, half-o per duplicate lane pair.
// LDS 48.5KB -> 3 blocks/CU -> 24 waves/CU (1.5x R5's TLP).
__global__ __launch_bounds__(NW * 64, 2)
void mask_attn_fused(const float* __restrict__ value, const float* __restrict__ key,
                     const int* __restrict__ seq_len, const float* __restrict__ w1,
                     const float* __restrict__ b1, const float* __restrict__ w2,
                     const float* __restrict__ fcw, const float* __restrict__ fcb,
                     float* __restrict__ out, int B) {
    __shared__ short8 wlds[2048];          // 32 KiB: Wk -> Wv -> (fcw_hi|fcw_lo)
    __shared__ unsigned vstage[NW][512];   // 16 KiB: per-wave bf16 value tile (swizzled)
    __shared__ f32x4 w2lds4[32];           // 512 B

    const int tid = threadIdx.x;
    const int wave = tid >> 6;
    const int lane = tid & 63;
    const int g = lane >> 4;     // 0..3
    const int lo = lane & 15;    // 0..15 (col); batch = lo&7, cols 8-15 duplicate
    const int b = lo & 7;
    const int lrow = lane >> 5;  // 0..1
    const int lcol = lane & 31;  // 16B chunk within 512B row

    long long b0w = (long long)blockIdx.x * BPB + (long long)wave * BPW;
    if (b0w > (long long)B - BPW) b0w = (long long)B - BPW;  // duplicate-safe clamp
    const long long vb = b0w + b;

    // ---------- prologue: coalesced issue of tiles 0,1 + key, before staging ------
    const float* vbase = value + (size_t)b0w * 1152;
    f32x4 xfA[4], xfB[4];
    issue_tile(vbase, 0, lrow, lcol, xfA);
    issue_tile(vbase, 1, lrow, lcol, xfB);

    f32x4 kv[8];
    const float* kp = key + vb * 128 + g * 8;
#pragma unroll
    for (int h = 0; h < 8; ++h)
        kv[h] = *(const f32x4*)(kp + (h >> 1) * 32 + (h & 1) * 4);

    if (tid < 32) w2lds4[tid] = ((const f32x4*)w2)[tid];

    // ---------- phase 1: Wk fragments -> LDS ----------
    stage_bfrags(w1, 2 * 128, 0, 8, wlds, tid);
    __syncthreads();

    // ---------- phase 2 (swapped): hk[h][b] = b1[h] + Wk·key^T, kept in regs ------
    unsigned hkp[8][2];
    {
        short8 kf[4];
#pragma unroll
        for (int kt = 0; kt < 4; ++kt)
            kf[kt] = pack_frag(kv[2 * kt], kv[2 * kt + 1]);
#pragma unroll
        for (int ct = 0; ct < 8; ++ct) {
            f32x4 acc = *(const f32x4*)(b1 + ct * 16 + g * 4);
#pragma unroll
            for (int kt = 0; kt < 4; ++kt)
                acc = __builtin_amdgcn_mfma_f32_16x16x32_bf16(
                    wlds[(kt * 8 + ct) * 64 + lane], kf[kt], acc, 0, 0, 0);
            hkp[ct][0] = rne_bf16_pair(acc.x, acc.y);
            hkp[ct][1] = rne_bf16_pair(acc.z, acc.w);
        }
    }
    __syncthreads();

    // ---------- phase 3: Wv fragments -> LDS ----------
    stage_bfrags(w1, 2 * 128, 128, 8, wlds, tid);
    __syncthreads();

    unsigned* vs = vstage[wave];
    commit_tile(vs, xfA, lrow, lcol);  // tile 0 (arrived during phases 1-3)
    const int sq = seq_len[vb];

    // ---------- phase 4: depth-2 pipelined fused l-loop ----------
    float o[2][8];
#pragma unroll
    for (int q = 0; q < 2; ++q)
#pragma unroll
        for (int j = 0; j < 8; ++j) o[q][j] = 0.f;
    float s = 0.f, m = -3e38f;

#pragma unroll 1
    for (int l = 0; l < 9; l += 2) {
        stepv(l, vs, wlds, hkp, w2lds4, vbase, lane, g, b, lo, lrow, lcol, sq,
              m, s, o, xfA, xfB);
        if (l + 1 < 9)
            stepv(l + 1, vs, wlds, hkp, w2lds4, vbase, lane, g, b, lo, lrow, lcol, sq,
                  m, s, o, xfB, xfA);
    }

    // ---------- recombine split o across duplicate-lane pairs (shfl_xor 8) -------
    float of[4][8];
#pragma unroll
    for (int q = 0; q < 2; ++q)
#pragma unroll
        for (int j = 0; j < 8; ++j) {
            float oth = __shfl_xor(o[q][j], 8);
            of[q][j]     = (lo < 8) ? o[q][j] : oth;   // kt 0,1
            of[2 + q][j] = (lo < 8) ? oth : o[q][j];   // kt 2,3
        }

    // normalize; split O into bf16 hi+lo fc A-fragments (row = lo, k = kt*32+g*8+j)
    const float rs = 1.f / s;
    short8 afoh[4], afol[4];
#pragma unroll
    for (int kt = 0; kt < 4; ++kt) {
        union { unsigned u[4]; short8 v; } uh, ul;
#pragma unroll
        for (int p = 0; p < 4; ++p) {
            float x = of[kt][2 * p] * rs, y = of[kt][2 * p + 1] * rs;
            unsigned hx = rne16(x), hy = rne16(y);
            uh.u[p] = hx | (hy << 16);
            ul.u[p] = rne_bf16_pair(x - __uint_as_float(hx << 16),
                                    y - __uint_as_float(hy << 16));
        }
        afoh[kt] = uh.v;
        afol[kt] = ul.v;
    }

    __syncthreads();
    // ---------- phase 5: fcw hi/lo fragments -> LDS ----------
    stage_bfrags_split(fcw, 128, 4, wlds, wlds + 1024, tid);
    __syncthreads();

    // ---------- phase 6: out = relu(O @ fcw^T + fcb), split-bf16 ----------
    // C rows 0..15 = batches (rows 8-15 duplicate); only g<2 lanes store.
    {
        f32x4 facc[4];
#pragma unroll
        for (int ct = 0; ct < 4; ++ct) {
            float fb = fcb[ct * 16 + lo];
            facc[ct] = (f32x4){fb, fb, fb, fb};
        }
#pragma unroll
        for (int kt = 0; kt < 4; ++kt)
#pragma unroll
            for (int ct = 0; ct < 4; ++ct) {
                short8 wh = wlds[(kt * 4 + ct) * 64 + lane];
                short8 wl = wlds[1024 + (kt * 4 + ct) * 64 + lane];
                facc[ct] = __builtin_amdgcn_mfma_f32_16x16x32_bf16(afoh[kt], wh, facc[ct], 0, 0, 0);
                facc[ct] = __builtin_amdgcn_mfma_f32_16x16x32_bf16(afol[kt], wh, facc[ct], 0, 0, 0);
                facc[ct] = __builtin_amdgcn_mfma_f32_16x16x32_bf16(afoh[kt], wl, facc[ct], 0, 0, 0);
            }
        if (g < 2) {
#pragma unroll
            for (int ct = 0; ct < 4; ++ct) {
                float v0 = fmaxf(facc[ct].x, 0.f), v1 = fmaxf(facc[ct].y, 0.f);
                float v2 = fmaxf(facc[ct].z, 0.f), v3 = fmaxf(facc[ct].w, 0.f);
                long long bo = b0w + g * 4;
                out[(bo + 0) * 64 + ct * 16 + lo] = v0;
                out[(bo + 1) * 64 + ct * 16 + lo] = v1;
                out[(bo + 2) * 64 + ct * 16 + lo] = v2;
                out[(bo + 3) * 64 + ct * 16 + lo] = v3;
            }
        }
    }
}

extern "C" void kernel_launch(void* const* d_in, const int* in_sizes, int n_in,
                              void* d_out, int out_size, void* d_ws, size_t ws_size,
                              hipStream_t stream) {
    const float* value = (const float*)d_in[0];
    const float* key   = (const float*)d_in[1];
    const int*   seq   = (const int*)d_in[2];
    // d_in[3] = maxlen (unused; L == 9 fixed by reference)
    const float* w1    = (const float*)d_in[4];
    const float* b1    = (const float*)d_in[5];
    const float* w2    = (const float*)d_in[6];
    // d_in[7] = b2: softmax-invariant, dropped
    const float* fcw   = (const float*)d_in[8];
    const float* fcb   = (const float*)d_in[9];
    float* out = (float*)d_out;

    int B = in_sizes[1] / 128;
    int blocks = (B + BPB - 1) / BPB;
    mask_attn_fused<<<blocks, NW * 64, 0, stream>>>(value, key, seq, w1, b1, w2, fcw, fcb, out, B);
}

// Round 13
// 88.975 us; speedup vs baseline: 4.1940x; 4.1940x over previous
//
#include <hip/hip_runtime.h>
#include <hip/hip_bf16.h>

typedef __attribute__((ext_vector_type(8))) short short8;   // 8 x bf16 bits = 4 VGPRs
typedef __attribute__((ext_vector_type(4))) float f32x4;

#define NW 8            // waves per block (512 threads)
#define BPW 16          // batches per wave
#define BPB (NW * BPW)  // 128 batches per block

static __device__ __forceinline__ unsigned pk_bf16(float a, float b) {
    unsigned d;
    asm("v_cvt_pk_bf16_f32 %0, %1, %2" : "=v"(d) : "v"(a), "v"(b));
    return d;
}

// round-to-nearest-even bf16, returning the 16 bits
static __device__ __forceinline__ unsigned rne16(float x) {
    unsigned u = __float_as_uint(x);
    return (u + 0x7fffu + ((u >> 16) & 1u)) >> 16;
}
static __device__ __forceinline__ unsigned rne_bf16_pair(float x, float y) {
    return rne16(x) | (rne16(y) << 16);
}

static __device__ __forceinline__ short8 pack_frag(f32x4 a, f32x4 b) {
    union { unsigned u[4]; short8 s; } u;
    u.u[0] = pk_bf16(a.x, a.y);
    u.u[1] = pk_bf16(a.z, a.w);
    u.u[2] = pk_bf16(b.x, b.y);
    u.u[3] = pk_bf16(b.z, b.w);
    return u.s;
}

// Stage fragments of W (W[n][k]) into LDS. Same lane map serves as A-frag
// (m = lane&15 -> row n of W) or B-frag: entry idx = (kt*nct + ct)*64 + lane;
// lane holds 8 bf16 with k = kt*32 + (lane>>4)*8 + j, outer = ct*16 + (lane&15).
static __device__ __forceinline__ void stage_bfrags(const float* __restrict__ w,
                                                    int row_stride, int k_off, int nct,
                                                    short8* lds, int tid) {
    const int total = 4 * nct * 64;
    for (int idx = tid; idx < total; idx += NW * 64) {
        int lane = idx & 63;
        int ct = (idx >> 6) % nct;
        int kt = idx / (64 * nct);
        int n = ct * 16 + (lane & 15);
        int k = kt * 32 + (lane >> 4) * 8;
        const float* p = w + (size_t)n * row_stride + k_off + k;
        f32x4 a = *(const f32x4*)p;
        f32x4 b = *(const f32x4*)(p + 4);
        lds[idx] = pack_frag(a, b);
    }
}

// Same, but split each element into bf16 hi + bf16 residual (hi -> lds_hi, lo -> lds_lo).
static __device__ __forceinline__ void stage_bfrags_split(const float* __restrict__ w,
                                                          int row_stride, int nct,
                                                          short8* lds_hi, short8* lds_lo,
                                                          int tid) {
    const int total = 4 * nct * 64;
    for (int idx = tid; idx < total; idx += NW * 64) {
        int lane = idx & 63;
        int ct = (idx >> 6) % nct;
        int kt = idx / (64 * nct);
        int n = ct * 16 + (lane & 15);
        int k = kt * 32 + (lane >> 4) * 8;
        const float* p = w + (size_t)n * row_stride + k;
        f32x4 a = *(const f32x4*)p;
        f32x4 b = *(const f32x4*)(p + 4);
        float xs[8] = {a.x, a.y, a.z, a.w, b.x, b.y, b.z, b.w};
        union { unsigned u[4]; short8 s; } uh, ul;
#pragma unroll
        for (int q = 0; q < 4; ++q) {
            float x = xs[2 * q], y = xs[2 * q + 1];
            unsigned hx = rne16(x), hy = rne16(y);
            uh.u[q] = hx | (hy << 16);
            ul.u[q] = rne_bf16_pair(x - __uint_as_float(hx << 16),
                                    y - __uint_as_float(hy << 16));
        }
        lds_hi[idx] = uh.s;
        lds_lo[idx] = ul.s;
    }
}

// MEASURED launch-bounds rule on gfx950 hipcc: VGPR cap = 256/arg, independent
// of block size ((512,4)->64, (512,3)->84, (256,3)->84, (512,2)->128).
// FINAL STRUCTURE (session best, 89.1 us): single-read fused kernel at 16
// waves/CU. Swapped logit GEMM (weights A from LDS, value B in regs) so the
// per-l cross-lane reduce is 2 shfl_xor; flash softmax; fp32 o-update from the
// live loads; split-bf16 fc epilogue. Structural ceiling evidence: three
// different inner loops (serial/pipelined/swapped) all measure 89-90 us at 16
// waves/CU; >16 waves needs <=85 VGPR (unreachable: o32+raw32+hk16+frag16),
// and every deeper restructure (depth-2, coalesce+LDS-transpose) spilled at
// the 128 cap (R10/R11/R12: 292-427 us).
__global__ __launch_bounds__(NW * 64, 2)
void mask_attn_fused(const float* __restrict__ value, const float* __restrict__ key,
                     const int* __restrict__ seq_len, const float* __restrict__ w1,
                     const float* __restrict__ b1, const float* __restrict__ w2,
                     const float* __restrict__ fcw, const float* __restrict__ fcb,
                     float* __restrict__ out, int B) {
    __shared__ short8 wlds[2048];            // 32 KiB: Wk -> Wv -> (fcw_hi|fcw_lo)
    __shared__ uint2 hklds[NW * 8 * 64];     // 32 KiB: per-wave hk^T init (bf16-pair bits)
    __shared__ f32x4 w2lds4[32];             // 512 B: w2 as f32x4[ct*4+g]

    const int tid = threadIdx.x;
    const int wave = tid >> 6;
    const int lane = tid & 63;
    const int g = lane >> 4;   // 0..3
    const int lo = lane & 15;  // 0..15

    const long long b0w = (long long)blockIdx.x * BPB + (long long)wave * BPW;
    long long vb = b0w + lo; if (vb > (long long)B - 1) vb = (long long)B - 1;

    // ---------- prologue: issue tile-0 value loads + key loads FIRST ----------
    const float* ap = value + vb * (9 * 128) + g * 8;
    f32x4 raw[8];
#pragma unroll
    for (int h = 0; h < 8; ++h)
        raw[h] = *(const f32x4*)(ap + (h >> 1) * 32 + (h & 1) * 4);
    f32x4 kv[8];
    const float* kp = key + vb * 128 + g * 8;
#pragma unroll
    for (int h = 0; h < 8; ++h)
        kv[h] = *(const f32x4*)(kp + (h >> 1) * 32 + (h & 1) * 4);

    if (tid < 32) w2lds4[tid] = ((const f32x4*)w2)[tid];

    // ---------- phase 1: Wk fragments -> LDS ----------
    stage_bfrags(w1, 2 * 128, 0, 8, wlds, tid);
    __syncthreads();

    // ---------- phase 2 (swapped): C2[h][b] = b1[h] + Wk·key^T ----------
    // C/D layout: row h = ct*16 + g*4 + reg, col b = lane&15.
    {
        short8 kf[4];
#pragma unroll
        for (int kt = 0; kt < 4; ++kt)
            kf[kt] = pack_frag(kv[2 * kt], kv[2 * kt + 1]);
#pragma unroll
        for (int ct = 0; ct < 8; ++ct) {
            f32x4 acc = *(const f32x4*)(b1 + ct * 16 + g * 4);  // rows g*4..g*4+3
#pragma unroll
            for (int kt = 0; kt < 4; ++kt)
                acc = __builtin_amdgcn_mfma_f32_16x16x32_bf16(
                    wlds[(kt * 8 + ct) * 64 + lane], kf[kt], acc, 0, 0, 0);
            uint2 pk;
            pk.x = rne_bf16_pair(acc.x, acc.y);
            pk.y = rne_bf16_pair(acc.z, acc.w);
            hklds[wave * 512 + ct * 64 + lane] = pk;
        }
    }
    __syncthreads();

    // ---------- phase 3: Wv fragments -> LDS ----------
    stage_bfrags(w1, 2 * 128, 128, 8, wlds, tid);
    __syncthreads();

    const int sq = seq_len[vb];  // valid positions: l <= sq (this lane's batch = lo)
    const uint2* hkw = hklds + wave * 512;

    // ---------- phase 4: pipelined fused l-loop (swapped GEMM) ----------
    float o[4][8];
#pragma unroll
    for (int kt = 0; kt < 4; ++kt)
#pragma unroll
        for (int j = 0; j < 8; ++j) o[kt][j] = 0.f;
    float s = 0.f, m = -3e38f;

#pragma unroll 1
    for (int l = 0; l < 9; ++l) {
        // convert: raw -> af (bf16 hi) + alo (bf16 residual); then raw is reusable
        short8 af[4], alo[4];
#pragma unroll
        for (int kt = 0; kt < 4; ++kt) {
            f32x4 a = raw[2 * kt], b = raw[2 * kt + 1];
            af[kt] = pack_frag(a, b);
            float xs[8] = {a.x, a.y, a.z, a.w, b.x, b.y, b.z, b.w};
            union { unsigned u[4]; short8 s; } ul;
#pragma unroll
            for (int q = 0; q < 4; ++q) {
                float x = xs[2 * q], y = xs[2 * q + 1];
                unsigned hx = rne16(x), hy = rne16(y);
                ul.u[q] = pk_bf16(x - __uint_as_float(hx << 16),
                                  y - __uint_as_float(hy << 16));
            }
            alo[kt] = ul.s;
        }
        // issue next tile's loads into raw (in flight under the whole chain below)
        if (l + 1 < 9) {
#pragma unroll
            for (int h = 0; h < 8; ++h)
                raw[h] = *(const f32x4*)(ap + (l + 1) * 128 + (h >> 1) * 32 + (h & 1) * 4);
        }

        // swapped logit GEMM: acc[h-tile][b], weights A from LDS, value B in regs.
        float pA = 0.f, pB = 0.f;
#pragma unroll
        for (int ct = 0; ct < 8; ++ct) {
            uint2 hkv = hkw[ct * 64 + lane];
            f32x4 acc;
            acc.x = __uint_as_float(hkv.x << 16);
            acc.y = __uint_as_float(hkv.x & 0xffff0000u);
            acc.z = __uint_as_float(hkv.y << 16);
            acc.w = __uint_as_float(hkv.y & 0xffff0000u);
#pragma unroll
            for (int kt = 0; kt < 4; ++kt)
                acc = __builtin_amdgcn_mfma_f32_16x16x32_bf16(
                    wlds[(kt * 8 + ct) * 64 + lane], af[kt], acc, 0, 0, 0);
            f32x4 wv = w2lds4[ct * 4 + g];  // w2[ct*16+g*4 .. +3], broadcast read
            if (ct & 1) {
                pB += fmaxf(acc.x, 0.f) * wv.x;
                pB += fmaxf(acc.y, 0.f) * wv.y;
                pB += fmaxf(acc.z, 0.f) * wv.z;
                pB += fmaxf(acc.w, 0.f) * wv.w;
            } else {
                pA += fmaxf(acc.x, 0.f) * wv.x;
                pA += fmaxf(acc.y, 0.f) * wv.y;
                pA += fmaxf(acc.z, 0.f) * wv.z;
                pA += fmaxf(acc.w, 0.f) * wv.w;
            }
        }
        float p = pA + pB;
        p += __shfl_xor(p, 16);
        p += __shfl_xor(p, 32);
        float w = p;  // logit of batch lo, present in every lane of the column

        // flash update (masked l: no-op)
        bool valid = (l <= sq);
        float mn = valid ? fmaxf(m, w) : m;
        float c = __expf(m - mn);              // ==1 when max unchanged; ==0 on first l
        float e = valid ? __expf(w - mn) : 0.f;
        s = s * c + e;
        m = mn;
        // o-update from hi+lo (exact fp32 sum of the two bf16 parts)
#pragma unroll
        for (int kt = 0; kt < 4; ++kt) {
            union { short8 v; unsigned u[4]; } uh, ul;
            uh.v = af[kt];
            ul.v = alo[kt];
#pragma unroll
            for (int q = 0; q < 4; ++q) {
                float h0 = __uint_as_float(uh.u[q] << 16);
                float h1 = __uint_as_float(uh.u[q] & 0xffff0000u);
                float l0 = __uint_as_float(ul.u[q] << 16);
                float l1 = __uint_as_float(ul.u[q] & 0xffff0000u);
                o[kt][2 * q]     = o[kt][2 * q] * c + e * (h0 + l0);
                o[kt][2 * q + 1] = o[kt][2 * q + 1] * c + e * (h1 + l1);
            }
        }
    }

    // normalize; split O into bf16 hi+lo fc A-fragments (row = lo, k = kt*32+g*8+j)
    const float rs = 1.f / s;  // s>0 always: l=0 is always valid (sq >= 0)
    short8 afoh[4], afol[4];
#pragma unroll
    for (int kt = 0; kt < 4; ++kt) {
        union { unsigned u[4]; short8 v; } uh, ul;
#pragma unroll
        for (int p = 0; p < 4; ++p) {
            float x = o[kt][2 * p] * rs, y = o[kt][2 * p + 1] * rs;
            unsigned hx = rne16(x), hy = rne16(y);
            uh.u[p] = hx | (hy << 16);
            ul.u[p] = rne_bf16_pair(x - __uint_as_float(hx << 16),
                                    y - __uint_as_float(hy << 16));
        }
        afoh[kt] = uh.v;
        afol[kt] = ul.v;
    }

    __syncthreads();
    // ---------- phase 5: fcw hi/lo fragments -> LDS (hi: [0,1024), lo: [1024,2048)) --
    stage_bfrags_split(fcw, 128, 4, wlds, wlds + 1024, tid);
    __syncthreads();

    // ---------- phase 6: out = relu(O @ fcw^T + fcb), split-bf16 (3 cross terms) ----
    {
        f32x4 facc[4];
#pragma unroll
        for (int ct = 0; ct < 4; ++ct) {
            float fb = fcb[ct * 16 + lo];
            facc[ct] = (f32x4){fb, fb, fb, fb};
        }
#pragma unroll
        for (int kt = 0; kt < 4; ++kt)
#pragma unroll
            for (int ct = 0; ct < 4; ++ct) {
                short8 wh = wlds[(kt * 4 + ct) * 64 + lane];
                short8 wl = wlds[1024 + (kt * 4 + ct) * 64 + lane];
                facc[ct] = __builtin_amdgcn_mfma_f32_16x16x32_bf16(afoh[kt], wh, facc[ct], 0, 0, 0);
                facc[ct] = __builtin_amdgcn_mfma_f32_16x16x32_bf16(afol[kt], wh, facc[ct], 0, 0, 0);
                facc[ct] = __builtin_amdgcn_mfma_f32_16x16x32_bf16(afoh[kt], wl, facc[ct], 0, 0, 0);
            }
#pragma unroll
        for (int ct = 0; ct < 4; ++ct) {
            float v0 = fmaxf(facc[ct].x, 0.f), v1 = fmaxf(facc[ct].y, 0.f);
            float v2 = fmaxf(facc[ct].z, 0.f), v3 = fmaxf(facc[ct].w, 0.f);
            long long bo = b0w + g * 4;
            if (bo + 0 < B) out[(bo + 0) * 64 + ct * 16 + lo] = v0;
            if (bo + 1 < B) out[(bo + 1) * 64 + ct * 16 + lo] = v1;
            if (bo + 2 < B) out[(bo + 2) * 64 + ct * 16 + lo] = v2;
            if (bo + 3 < B) out[(bo + 3) * 64 + ct * 16 + lo] = v3;
        }
    }
}

extern "C" void kernel_launch(void* const* d_in, const int* in_sizes, int n_in,
                              void* d_out, int out_size, void* d_ws, size_t ws_size,
                              hipStream_t stream) {
    const float* value = (const float*)d_in[0];
    const float* key   = (const float*)d_in[1];
    const int*   seq   = (const int*)d_in[2];
    // d_in[3] = maxlen (unused; L == 9 fixed by reference)
    const float* w1    = (const float*)d_in[4];
    const float* b1    = (const float*)d_in[5];
    const float* w2    = (const float*)d_in[6];
    // d_in[7] = b2: softmax-invariant, dropped
    const float* fcw   = (const float*)d_in[8];
    const float* fcb   = (const float*)d_in[9];
    float* out = (float*)d_out;

    int B = in_sizes[1] / 128;
    int blocks = (B + BPB - 1) / BPB;
    mask_attn_fused<<<blocks, NW * 64, 0, stream>>>(value, key, seq, w1, b1, w2, fcw, fcb, out, B);
}